// Round 4
// baseline (123.507 us; speedup 1.0000x reference)
//
#include <hip/hip_runtime.h>
#include <math.h>

// Problem constants (setup_inputs: S=2048, U=10, D=256)
#define SS   2048
#define UU   10
#define DD   256
#define BB   (SS * UU)   // 20480 rows
#define EPSF 1e-8f

typedef __attribute__((ext_vector_type(8))) short   bf16x8;
typedef __attribute__((ext_vector_type(4))) float   floatx4;

__device__ static inline unsigned short f2bf(float f) {
    union { float f; unsigned u; } v; v.f = f;
    unsigned r = (v.u + 0x7FFFu + ((v.u >> 16) & 1u)) >> 16;  // RNE
    return (unsigned short)r;
}

__device__ static inline void gl_lds16(const unsigned short* g, unsigned short* l) {
    // 16B per lane; LDS dest = wave-uniform base + lane*16
    __builtin_amdgcn_global_load_lds((const __attribute__((address_space(1))) void*)g,
                                     (__attribute__((address_space(3))) void*)l, 16, 0, 0);
}

// ---- Kernel 1 (fused prep): normalize rows -> Enb, centroid+normalize -> Cnb,
//      zero sumexp (and out). Centroid-norm reduce now wave-shuffle based
//      (1 barrier instead of 8). ----
__global__ __launch_bounds__(256) void prep_kernel(const float* __restrict__ E,
                                                   unsigned short* __restrict__ Enb,
                                                   unsigned short* __restrict__ Cnb,
                                                   float* __restrict__ sumexp,
                                                   float* __restrict__ out) {
    const int s   = blockIdx.x;
    const int wid = threadIdx.x >> 6, lane = threadIdx.x & 63;
    __shared__ float cent[4][256];
    __shared__ float part[4];

    if (threadIdx.x < UU) sumexp[s * UU + threadIdx.x] = 0.f;
    if (s == 0 && threadIdx.x == 0) out[0] = 0.f;

    float cp0 = 0.f, cp1 = 0.f, cp2 = 0.f, cp3 = 0.f;
    for (int u = wid; u < UU; u += 4) {
        const size_t roff = (size_t)(s * UU + u) * DD;
        float4 v = ((const float4*)(E + roff))[lane];
        float ssq = v.x * v.x + v.y * v.y + v.z * v.z + v.w * v.w;
#pragma unroll
        for (int off = 32; off; off >>= 1) ssq += __shfl_xor(ssq, off, 64);
        const float rinv = 1.0f / fmaxf(sqrtf(ssq), EPSF);
        ushort4 o;
        o.x = f2bf(v.x * rinv); o.y = f2bf(v.y * rinv);
        o.z = f2bf(v.z * rinv); o.w = f2bf(v.w * rinv);
        ((ushort4*)(Enb + roff))[lane] = o;
        cp0 += v.x; cp1 += v.y; cp2 += v.z; cp3 += v.w;
    }
    cent[wid][lane * 4 + 0] = cp0;
    cent[wid][lane * 4 + 1] = cp1;
    cent[wid][lane * 4 + 2] = cp2;
    cent[wid][lane * 4 + 3] = cp3;
    __syncthreads();

    const int d = threadIdx.x;
    const float c = (cent[0][d] + cent[1][d] + cent[2][d] + cent[3][d]) * 0.1f;
    float p = c * c;
#pragma unroll
    for (int off = 32; off; off >>= 1) p += __shfl_xor(p, off, 64);
    if (lane == 0) part[wid] = p;
    __syncthreads();
    const float tot = part[0] + part[1] + part[2] + part[3];
    const float rinv = 1.0f / fmaxf(sqrtf(tot), EPSF);
    Cnb[(size_t)s * DD + d] = f2bf(c * rinv);
}

// ---- Kernel 2: bf16 MFMA GEMM (Enb x Cnb^T) fused with exp-sum + pos ----
// Round-4 schedule: verified round-0 core (128x128 tile, 2x2 waves, 4x4
// 16x16x32 tiles, BK=32, swizzled LDS granules, fused-LSE epilogue) with a
// 4-SLOT ROTATING LDS PIPELINE + COUNTED VMCNT (T3+T4):
//   per step t: vmcnt(4) [stage(t) landed; stage(t+1) stays in flight]
//               -> s_barrier -> issue stage(t+2) into slot (t+2)&3
//               -> ds_read slot t&3 -> 16 MFMA (setprio-wrapped).
//   Never drains vmcnt to 0 until the final step; ONE barrier per step.
//   WAR safe: slot written at step t was last ds_read at step t-2, and those
//   reads complete (lgkmcnt before MFMA) before the top-of-(t-1) barrier.
//   RAW safe: own vmcnt(4) + barrier => all waves' stage(t) data in LDS.
// LDS = 4 slots x 8 KB x {A,B} = 64 KB -> 2 blocks/CU (matches measured
// residency anyway). XCD-bijective swizzle restored (FETCH 70->9 MB).
#define BM  128
#define BN  128
#define BK  32
#define NCK 8                 // DD / BK
#define CHUNK (BM * BK)       // 4096 shorts = 8 KB per slot per operand

__device__ __forceinline__ void chunk_mfma(const unsigned short* Ab,
                                           const unsigned short* Bb,
                                           const int* aoff, const int* boff,
                                           floatx4 (&acc)[4][4]) {
    bf16x8 af[4], bfr[4];
#pragma unroll
    for (int t = 0; t < 4; ++t) af[t]  = *(const bf16x8*)(Ab + aoff[t]);
#pragma unroll
    for (int t = 0; t < 4; ++t) bfr[t] = *(const bf16x8*)(Bb + boff[t]);
    __builtin_amdgcn_s_setprio(1);
#pragma unroll
    for (int mt = 0; mt < 4; ++mt)
#pragma unroll
        for (int nt = 0; nt < 4; ++nt)
            acc[mt][nt] = __builtin_amdgcn_mfma_f32_16x16x32_bf16(af[mt], bfr[nt], acc[mt][nt], 0, 0, 0);
    __builtin_amdgcn_s_setprio(0);
}

__global__ __launch_bounds__(256) void gemm_lse_kernel(const unsigned short* __restrict__ Enb,
                                                       const unsigned short* __restrict__ Cnb,
                                                       float* __restrict__ posArr,
                                                       float* __restrict__ sumexp) {
    __shared__ unsigned short As[4 * CHUNK];   // 32 KB: slot k at As + (k&3)*CHUNK
    __shared__ unsigned short Bs[4 * CHUNK];   // 32 KB

    const int tid  = threadIdx.x;
    const int wid  = tid >> 6, lane = tid & 63;
    const int l15  = lane & 15, quad = lane >> 4;
    const int wave_m = wid >> 1, wave_n = wid & 1;

    // XCD-aware bijective swizzle: grid 2560 = 8 XCDs x 320 contiguous blocks;
    // within an XCD bn runs fastest -> each A panel is fetched by ONE XCD's L2.
    const int swz = (blockIdx.x & 7) * 320 + (blockIdx.x >> 3);
    const int bn = swz & 15;                 // SS/BN = 16
    const int bm = swz >> 4;                 // BB/BM = 160
    const int row0 = bm * BM, n0 = bn * BN;

    // staging map (per chunk): 16 sub-chunks of 1 KB (16 rows x 32k);
    // A: c=0..7, B: c=8..15; 4 per wave. lane -> row rl=lane>>2, slot sl=lane&3;
    // fetch logical granule sl^((rl>>1)&3) (pre-swizzled global source,
    // linear LDS dest -> consistent with the fragment-read swizzle).
    const int rl = lane >> 2;
    const int gf = ((lane & 3) ^ ((rl >> 1) & 3)) * 8;
    const unsigned short* gp[4];
    unsigned short* lp[4];
#pragma unroll
    for (int i = 0; i < 4; ++i) {
        const int c = wid * 4 + i;
        if (c < 8) {
            gp[i] = Enb + (size_t)(row0 + c * 16 + rl) * DD + gf;
            lp[i] = As + c * 512;
        } else {
            gp[i] = Cnb + (size_t)(n0 + (c - 8) * 16 + rl) * DD + gf;
            lp[i] = Bs + (c - 8) * 512;
        }
    }

    // fragment offsets (within a slot): row r = wtile*16 + l15,
    // elem = r*BK + (quad^((l15>>1)&3))*8  -- verified conflict-free
    const int fswz = (quad ^ ((l15 >> 1) & 3)) * 8;
    int aoff[4], boff[4];
#pragma unroll
    for (int t = 0; t < 4; ++t) {
        aoff[t] = (wave_m * 64 + t * 16 + l15) * BK + fswz;
        boff[t] = (wave_n * 64 + t * 16 + l15) * BK + fswz;
    }

    floatx4 acc[4][4];
#pragma unroll
    for (int i = 0; i < 4; ++i)
#pragma unroll
        for (int j = 0; j < 4; ++j) acc[i][j] = (floatx4){0.f, 0.f, 0.f, 0.f};

    // ---- prologue: issue stage(0) and stage(1) (8 loads in flight) ----
#pragma unroll
    for (int i = 0; i < 4; ++i) gl_lds16(gp[i], lp[i]);
#pragma unroll
    for (int i = 0; i < 4; ++i) gl_lds16(gp[i] + BK, lp[i] + CHUNK);

    // ---- pipelined K-loop: 8 steps, counted vmcnt, one barrier/step ----
#define GSTEP(T, VM, ISSUE)                                                  \
    asm volatile("s_waitcnt vmcnt(" #VM ")" ::: "memory");                   \
    __builtin_amdgcn_s_barrier();                                            \
    __builtin_amdgcn_sched_barrier(0);                                       \
    if (ISSUE) {                                                             \
        _Pragma("unroll")                                                    \
        for (int i = 0; i < 4; ++i)                                          \
            gl_lds16(gp[i] + ((T) + 2) * BK, lp[i] + (((T) + 2) & 3) * CHUNK); \
    }                                                                        \
    chunk_mfma(As + ((T) & 3) * CHUNK, Bs + ((T) & 3) * CHUNK, aoff, boff, acc);

    GSTEP(0, 4, 1) GSTEP(1, 4, 1) GSTEP(2, 4, 1) GSTEP(3, 4, 1)
    GSTEP(4, 4, 1) GSTEP(5, 4, 1) GSTEP(6, 4, 0) GSTEP(7, 0, 0)
#undef GSTEP

    // epilogue (register-only; no barrier needed): C/D layout col=l15 (n),
    // row=quad*4+reg (m); labels hoisted; exp-accumulate then one reduce pass.
    int lbl[4][4];
    float rs[4][4];
#pragma unroll
    for (int mt = 0; mt < 4; ++mt) {
        const int growb = row0 + wave_m * 64 + mt * 16 + quad * 4;
#pragma unroll
        for (int r = 0; r < 4; ++r) {
            lbl[mt][r] = (growb + r) / UU;
            rs[mt][r]  = 0.f;
        }
    }
#pragma unroll
    for (int mt = 0; mt < 4; ++mt) {
        const int growb = row0 + wave_m * 64 + mt * 16 + quad * 4;
#pragma unroll
        for (int nt = 0; nt < 4; ++nt) {
            const int col = n0 + wave_n * 64 + nt * 16 + l15;
#pragma unroll
            for (int r = 0; r < 4; ++r) {
                const float sim = acc[mt][nt][r];
                if (col == lbl[mt][r]) {
                    posArr[growb + r] = sim;     // excluded from sum (-inf mask)
                } else {
                    rs[mt][r] += __expf(sim);
                }
            }
        }
    }
#pragma unroll
    for (int mt = 0; mt < 4; ++mt) {
        const int growb = row0 + wave_m * 64 + mt * 16 + quad * 4;
#pragma unroll
        for (int m = 1; m < 16; m <<= 1) {
#pragma unroll
            for (int r = 0; r < 4; ++r) rs[mt][r] += __shfl_xor(rs[mt][r], m, 64);
        }
        if (l15 == 0) {
#pragma unroll
            for (int r = 0; r < 4; ++r) atomicAdd(&sumexp[growb + r], rs[mt][r]);
        }
    }
}

// ---- Kernel 3: single-pass finalize: mean of (-pos + log(sumexp)) ----
__global__ __launch_bounds__(256) void finalize_kernel(const float* __restrict__ posArr,
                                                       const float* __restrict__ sumexp,
                                                       float* __restrict__ out) {
    __shared__ float sred[256];
    const int tid = threadIdx.x;
    const int r = blockIdx.x * 256 + tid;
    sred[tid] = logf(sumexp[r]) - posArr[r];
    __syncthreads();
#pragma unroll
    for (int off = 128; off; off >>= 1) {
        if (tid < off) sred[tid] += sred[tid + off];
        __syncthreads();
    }
    if (tid == 0) atomicAdd(out, sred[0] * (1.0f / (float)BB));
}

extern "C" void kernel_launch(void* const* d_in, const int* in_sizes, int n_in,
                              void* d_out, int out_size, void* d_ws, size_t ws_size,
                              hipStream_t stream) {
    const float* E = (const float*)d_in[0];
    float* out = (float*)d_out;

    unsigned short* Enb = (unsigned short*)d_ws;            // BB*DD bf16 = 10.5 MB
    unsigned short* Cnb = Enb + (size_t)BB * DD;            // SS*DD bf16 = 1 MB
    float* posArr = (float*)(Cnb + (size_t)SS * DD);        // BB floats
    float* sumexp = posArr + BB;                            // BB floats (zeroed by prep)

    prep_kernel<<<SS, 256, 0, stream>>>(E, Enb, Cnb, sumexp, out);
    gemm_lse_kernel<<<(BB / BM) * (SS / BN), 256, 0, stream>>>(Enb, Cnb, posArr, sumexp);
    finalize_kernel<<<BB / 256, 256, 0, stream>>>(posArr, sumexp, out);
}

// Round 5
// 121.908 us; speedup vs baseline: 1.0131x; 1.0131x over previous
//
#include <hip/hip_runtime.h>
#include <math.h>

// Problem constants (setup_inputs: S=2048, U=10, D=256)
#define SS   2048
#define UU   10
#define DD   256
#define BB   (SS * UU)   // 20480 rows
#define EPSF 1e-8f

typedef __attribute__((ext_vector_type(8))) short   bf16x8;
typedef __attribute__((ext_vector_type(4))) float   floatx4;

__device__ static inline unsigned short f2bf(float f) {
    union { float f; unsigned u; } v; v.f = f;
    unsigned r = (v.u + 0x7FFFu + ((v.u >> 16) & 1u)) >> 16;  // RNE
    return (unsigned short)r;
}

__device__ static inline void gl_lds16(const unsigned short* g, unsigned short* l) {
    // 16B per lane; LDS dest = wave-uniform base + lane*16
    __builtin_amdgcn_global_load_lds((const __attribute__((address_space(1))) void*)g,
                                     (__attribute__((address_space(3))) void*)l, 16, 0, 0);
}

// ---- Kernel 1 (fused prep): normalize rows -> Enb, centroid+normalize -> Cnb,
//      zero sumexp (and out). ----
__global__ __launch_bounds__(256) void prep_kernel(const float* __restrict__ E,
                                                   unsigned short* __restrict__ Enb,
                                                   unsigned short* __restrict__ Cnb,
                                                   float* __restrict__ sumexp,
                                                   float* __restrict__ out) {
    const int s   = blockIdx.x;
    const int wid = threadIdx.x >> 6, lane = threadIdx.x & 63;
    __shared__ float cent[4][256];
    __shared__ float part[4];

    if (threadIdx.x < UU) sumexp[s * UU + threadIdx.x] = 0.f;
    if (s == 0 && threadIdx.x == 0) out[0] = 0.f;

    float cp0 = 0.f, cp1 = 0.f, cp2 = 0.f, cp3 = 0.f;
    for (int u = wid; u < UU; u += 4) {
        const size_t roff = (size_t)(s * UU + u) * DD;
        float4 v = ((const float4*)(E + roff))[lane];
        float ssq = v.x * v.x + v.y * v.y + v.z * v.z + v.w * v.w;
#pragma unroll
        for (int off = 32; off; off >>= 1) ssq += __shfl_xor(ssq, off, 64);
        const float rinv = 1.0f / fmaxf(sqrtf(ssq), EPSF);
        ushort4 o;
        o.x = f2bf(v.x * rinv); o.y = f2bf(v.y * rinv);
        o.z = f2bf(v.z * rinv); o.w = f2bf(v.w * rinv);
        ((ushort4*)(Enb + roff))[lane] = o;
        cp0 += v.x; cp1 += v.y; cp2 += v.z; cp3 += v.w;
    }
    cent[wid][lane * 4 + 0] = cp0;
    cent[wid][lane * 4 + 1] = cp1;
    cent[wid][lane * 4 + 2] = cp2;
    cent[wid][lane * 4 + 3] = cp3;
    __syncthreads();

    const int d = threadIdx.x;
    const float c = (cent[0][d] + cent[1][d] + cent[2][d] + cent[3][d]) * 0.1f;
    float p = c * c;
#pragma unroll
    for (int off = 32; off; off >>= 1) p += __shfl_xor(p, off, 64);
    if (lane == 0) part[wid] = p;
    __syncthreads();
    const float tot = part[0] + part[1] + part[2] + part[3];
    const float rinv = 1.0f / fmaxf(sqrtf(tot), EPSF);
    Cnb[(size_t)s * DD + d] = f2bf(c * rinv);
}

// ---- Kernel 2: bf16 MFMA GEMM (Enb x Cnb^T) fused with exp-sum + pos ----
// Round-5: m201-class geometry (the ONLY structure where phase pipelining is
// measured to pay on gfx950; 128-tile pipelining is documented-null m232):
//   BM=BN=256, BK=64, 512 thr = 8 waves (2M x 4N), per-wave 128x64 output,
//   LDS = 2 sides x (A 32KB + B 32KB) = 128 KB, 1 block/CU.
//   4 K-tiles x 4 phases; phase = { 8 ds_read_b128 frags | staged prefetch of
//   tile t+1 into side s^1 (phases 0-1) | barrier | lgkmcnt(0) | 16 MFMA
//   setprio-wrapped | barrier }. Tile boundary = vmcnt(0)+barrier (cheap:
//   prefetch had >=3 phases of flight). Staged bytes HALVED vs 128-tile
//   (4 B/output-elem); atomics halved (8 bn-blocks/row).
// LDS layout: row-major [256][64] bf16 per operand-side, granule g (16B) of
// row r stored at slot g^(r&7)  -> worst 2-way read conflict (free, m136).
// Staged via pre-swizzled GLOBAL source + linear LDS dest (both-sides rule).
#define BMg 256
#define BNg 256
#define BKg 64
#define NTg 4                   // DD / BKg
#define TSH (BMg * BKg)         // 16384 shorts = 32 KB per operand per side

__global__ __launch_bounds__(512, 2) void gemm_lse_kernel(const unsigned short* __restrict__ Enb,
                                                          const unsigned short* __restrict__ Cnb,
                                                          float* __restrict__ posArr,
                                                          float* __restrict__ sumexp) {
    __shared__ unsigned short As[2 * TSH];   // 64 KB: side s at As + s*TSH
    __shared__ unsigned short Bs[2 * TSH];   // 64 KB

    const int tid  = threadIdx.x;
    const int wid  = tid >> 6, lane = tid & 63;
    const int l15  = lane & 15, quad = lane >> 4;
    const int wave_m = wid >> 2, wave_n = wid & 3;   // 2 x 4 waves

    // XCD-bijective swizzle: grid 640 = 8 XCDs x 80; bn fastest within XCD.
    const int swz = (blockIdx.x & 7) * 80 + (blockIdx.x >> 3);
    const int bn = swz & 7;                  // SS/BNg = 8
    const int bm = swz >> 3;                 // BB/BMg = 80
    const int row0 = bm * BMg, n0 = bn * BNg;

    // staging: per wave 8 instrs per K-tile (4 A + 4 B), instr i covers rows
    // [wid*32 + i*8, +8) x 64k (1 KB). lane -> row +(lane>>3), granule lane&7;
    // fetch global granule (lane&7)^(row&7) -> LDS slot p holds logical p^(r&7).
    const int rl8 = lane >> 3, gl = lane & 7;
    const unsigned short *gpa[4], *gpb[4];
    int lof[4];
#pragma unroll
    for (int i = 0; i < 4; ++i) {
        const int rw  = wid * 32 + i * 8 + rl8;
        const int gsw = (gl ^ (rw & 7)) * 8;
        gpa[i] = Enb + (size_t)(row0 + rw) * DD + gsw;
        gpb[i] = Cnb + (size_t)(n0  + rw) * DD + gsw;
        lof[i] = (wid * 32 + i * 8) * 64;    // wave-uniform LDS base (shorts)
    }

#define STAGE_A(T) { _Pragma("unroll") for (int i_ = 0; i_ < 4; ++i_) \
        gl_lds16(gpa[i_] + (T) * BKg, As + ((T) & 1) * TSH + lof[i_]); }
#define STAGE_B(T) { _Pragma("unroll") for (int i_ = 0; i_ < 4; ++i_) \
        gl_lds16(gpb[i_] + (T) * BKg, Bs + ((T) & 1) * TSH + lof[i_]); }

    // fragment addressing: A row = wave_m*128 + mh*64 + mt*16 + l15,
    // B row = wave_n*64 + nt*16 + l15; frag bytes = row*128 + ((kk*4+quad)^(l15&7))*16
    const int swq  = l15 & 7;
    const int arow = wave_m * 128 + l15;
    const int brow = wave_n * 64 + l15;

    floatx4 acc[8][4];
#pragma unroll
    for (int i = 0; i < 8; ++i)
#pragma unroll
        for (int j = 0; j < 4; ++j) acc[i][j] = (floatx4){0.f, 0.f, 0.f, 0.f};

#define PHASE(T, P, SA, SB, BOUND)                                            \
  {                                                                           \
    bf16x8 af_[4], bf_[4];                                                    \
    _Pragma("unroll")                                                         \
    for (int mt = 0; mt < 4; ++mt)                                            \
      af_[mt] = *(const bf16x8*)(As + ((T) & 1) * TSH +                       \
                 (arow + ((P) & 1) * 64 + mt * 16) * 64 +                     \
                 ((((P) >> 1) * 4 + quad) ^ swq) * 8);                        \
    _Pragma("unroll")                                                         \
    for (int nt = 0; nt < 4; ++nt)                                            \
      bf_[nt] = *(const bf16x8*)(Bs + ((T) & 1) * TSH +                       \
                 (brow + nt * 16) * 64 +                                      \
                 ((((P) >> 1) * 4 + quad) ^ swq) * 8);                        \
    if (SA) STAGE_A((T) + 1);                                                 \
    if (SB) STAGE_B((T) + 1);                                                 \
    __builtin_amdgcn_s_barrier();                                             \
    asm volatile("s_waitcnt lgkmcnt(0)" ::: "memory");                        \
    __builtin_amdgcn_sched_barrier(0);                                        \
    __builtin_amdgcn_s_setprio(1);                                            \
    _Pragma("unroll")                                                         \
    for (int mt = 0; mt < 4; ++mt)                                            \
      _Pragma("unroll")                                                       \
      for (int nt = 0; nt < 4; ++nt)                                          \
        acc[((P) & 1) * 4 + mt][nt] = __builtin_amdgcn_mfma_f32_16x16x32_bf16(\
            af_[mt], bf_[nt], acc[((P) & 1) * 4 + mt][nt], 0, 0, 0);          \
    __builtin_amdgcn_s_setprio(0);                                            \
    if (BOUND) {                                                              \
      asm volatile("s_waitcnt vmcnt(0)" ::: "memory");                        \
      __builtin_amdgcn_s_barrier();                                           \
      __builtin_amdgcn_sched_barrier(0);                                      \
    } else {                                                                  \
      __builtin_amdgcn_s_barrier();                                           \
    }                                                                         \
  }

    // prologue: stage tile 0, full drain (cold start)
    STAGE_A(0); STAGE_B(0);
    asm volatile("s_waitcnt vmcnt(0)" ::: "memory");
    __builtin_amdgcn_s_barrier();
    __builtin_amdgcn_sched_barrier(0);

    // 4 K-tiles x 4 phases; prefetch t+1 at phases 0 (A) and 1 (B);
    // boundary vmcnt(0)+barrier at phase 3 (prefetch had >=3 phases flight).
    PHASE(0, 0, 1, 0, 0) PHASE(0, 1, 0, 1, 0) PHASE(0, 2, 0, 0, 0) PHASE(0, 3, 0, 0, 1)
    PHASE(1, 0, 1, 0, 0) PHASE(1, 1, 0, 1, 0) PHASE(1, 2, 0, 0, 0) PHASE(1, 3, 0, 0, 1)
    PHASE(2, 0, 1, 0, 0) PHASE(2, 1, 0, 1, 0) PHASE(2, 2, 0, 0, 0) PHASE(2, 3, 0, 0, 1)
    PHASE(3, 0, 0, 0, 0) PHASE(3, 1, 0, 0, 0) PHASE(3, 2, 0, 0, 0) PHASE(3, 3, 0, 0, 0)
#undef PHASE
#undef STAGE_A
#undef STAGE_B

    // epilogue: C/D layout col=l15 (n), row=quad*4+reg (m); per-mt row pass
    // keeps register pressure flat (no 8x4 label/rs arrays live at once).
#pragma unroll
    for (int mt = 0; mt < 8; ++mt) {
        const int growb = row0 + wave_m * 128 + mt * 16 + quad * 4;
        float rs[4] = {0.f, 0.f, 0.f, 0.f};
        int lbl[4];
#pragma unroll
        for (int r = 0; r < 4; ++r) lbl[r] = (growb + r) / UU;
#pragma unroll
        for (int nt = 0; nt < 4; ++nt) {
            const int col = n0 + wave_n * 64 + nt * 16 + l15;
#pragma unroll
            for (int r = 0; r < 4; ++r) {
                const float sim = acc[mt][nt][r];
                if (col == lbl[r]) {
                    posArr[growb + r] = sim;     // excluded from sum (-inf mask)
                } else {
                    rs[r] += __expf(sim);
                }
            }
        }
#pragma unroll
        for (int m = 1; m < 16; m <<= 1) {
#pragma unroll
            for (int r = 0; r < 4; ++r) rs[r] += __shfl_xor(rs[r], m, 64);
        }
        if (l15 == 0) {
#pragma unroll
            for (int r = 0; r < 4; ++r) atomicAdd(&sumexp[growb + r], rs[r]);
        }
    }
}

// ---- Kernel 3: single-pass finalize: mean of (-pos + log(sumexp)) ----
__global__ __launch_bounds__(256) void finalize_kernel(const float* __restrict__ posArr,
                                                       const float* __restrict__ sumexp,
                                                       float* __restrict__ out) {
    __shared__ float sred[256];
    const int tid = threadIdx.x;
    const int r = blockIdx.x * 256 + tid;
    sred[tid] = logf(sumexp[r]) - posArr[r];
    __syncthreads();
#pragma unroll
    for (int off = 128; off; off >>= 1) {
        if (tid < off) sred[tid] += sred[tid + off];
        __syncthreads();
    }
    if (tid == 0) atomicAdd(out, sred[0] * (1.0f / (float)BB));
}

extern "C" void kernel_launch(void* const* d_in, const int* in_sizes, int n_in,
                              void* d_out, int out_size, void* d_ws, size_t ws_size,
                              hipStream_t stream) {
    const float* E = (const float*)d_in[0];
    float* out = (float*)d_out;

    unsigned short* Enb = (unsigned short*)d_ws;            // BB*DD bf16 = 10.5 MB
    unsigned short* Cnb = Enb + (size_t)BB * DD;            // SS*DD bf16 = 1 MB
    float* posArr = (float*)(Cnb + (size_t)SS * DD);        // BB floats
    float* sumexp = posArr + BB;                            // BB floats (zeroed by prep)

    prep_kernel<<<SS, 256, 0, stream>>>(E, Enb, Cnb, sumexp, out);
    gemm_lse_kernel<<<(BB / BMg) * (SS / BNg), 512, 0, stream>>>(Enb, Cnb, posArr, sumexp);
    finalize_kernel<<<BB / 256, 256, 0, stream>>>(posArr, sumexp, out);
}